// Round 8
// baseline (7332.618 us; speedup 1.0000x reference)
//
#include <hip/hip_runtime.h>
#include <cmath>
#include <cstdint>

#define D_IN   2048
#define D_HID  16384
#define BATCH  4096
#define NUMEL  (64 * BATCH)        /* 262144 = k * prod(batch dims) */

#define CAND_CAP (1u << 20)        /* 1M candidate slots (4 MiB); bucket ~326K */
#define CIDX_U32 8192              /* wsu + 8192 ; bytes [32768, 32768+4MiB) */

#define DIAG_CAP   777777.0f
#define DIAG_RANK  888888.0f
#define DIAG_EMPTY 999999.0f

/* ws layout (bytes): 0: u32 hist[4096] (16KB) | 16384: u32 ctrl[16]
   32768: u32 cand_idx[1M] (4MiB).  ws >= ~248MB proven in R1/R2 (bf16x3
   GEMM ran from ws+2MB..248MB without faulting). */

typedef float f32x4v __attribute__((ext_vector_type(4)));

/* =====================================================================
   GEMM reproducing OpenBLAS sgemm per-element summation BIT-EXACTLY
   (np.einsum -> tensordot -> dot -> sgemm on the test host):
     - K blocked [384,384,384,384,256,256] (GEMM_Q=384 + driver tail-split)
     - within a block: single sequential FMA chain, ascending k
       (SIMD spans M/N in the microkernel; K is sequential -> target-indep)
     - block partials added in block order (beta=0 -> first exact)
     - then + bias (separate rounded add), then relu
   ===================================================================== */
__global__ __launch_bounds__(256) void gemm_blas(const float* __restrict__ A,
                                                 const float* __restrict__ B,
                                                 const float* __restrict__ bias,
                                                 float* __restrict__ C) {
  __shared__ float sA[16][68];
  __shared__ float sB[16][68];
  int bm = blockIdx.y, bn = blockIdx.x;
  int tid = threadIdx.x;
  int tx = tid & 15, ty = tid >> 4;

  float csum[4][4] = {};   /* accumulated block partials */
  float acc[4][4]  = {};   /* current block FMA chain    */

  for (int kt = 0; kt < D_IN / 16; ++kt) {
    #pragma unroll
    for (int i = 0; i < 4; ++i) {
      int e = tid + i * 256;
      int row = e >> 4, kk = e & 15;
      sA[kk][row] = A[(size_t)(bm * 64 + row) * D_IN + kt * 16 + kk];
      sB[kk][row] = B[(size_t)(bn * 64 + row) * D_IN + kt * 16 + kk];
    }
    __syncthreads();
    #pragma unroll
    for (int kk = 0; kk < 16; ++kk) {
      float a[4], b[4];
      #pragma unroll
      for (int i = 0; i < 4; ++i) { a[i] = sA[kk][ty * 4 + i]; b[i] = sB[kk][tx * 4 + i]; }
      #pragma unroll
      for (int i = 0; i < 4; ++i)
        #pragma unroll
        for (int j = 0; j < 4; ++j)
          acc[i][j] = fmaf(a[i], b[j], acc[i][j]);   /* single-rounded FMA chain */
    }
    __syncthreads();
    /* OpenBLAS kc boundaries: after k = 384,768,1152,1536,1792 */
    if (kt == 23 || kt == 47 || kt == 71 || kt == 95 || kt == 111) {
      #pragma unroll
      for (int i = 0; i < 4; ++i)
        #pragma unroll
        for (int j = 0; j < 4; ++j) { csum[i][j] += acc[i][j]; acc[i][j] = 0.f; }
    }
  }

  #pragma unroll
  for (int i = 0; i < 4; ++i) {
    int m = bm * 64 + ty * 4 + i;
    #pragma unroll
    for (int j = 0; j < 4; ++j) {
      int n = bn * 64 + tx * 4 + j;
      float s = csum[i][j] + acc[i][j];      /* + final 256-wide block */
      float v = s + bias[n];
      C[(size_t)m * D_HID + n] = v > 0.f ? v : 0.f;
    }
  }
}

/* ---- pass 1: 4096-bin histogram of top-12 key bits (skip exact zeros) ---- */
__global__ void hist1_k(const f32x4v* __restrict__ f, uint32_t* __restrict__ wsu, int n4) {
  __shared__ uint32_t lh[4096];
  for (int i = threadIdx.x; i < 4096; i += 256) lh[i] = 0;
  __syncthreads();
  int stride = gridDim.x * 256;
  for (int i = blockIdx.x * 256 + threadIdx.x; i < n4; i += stride) {
    f32x4v v = f[i];
    #pragma unroll
    for (int c = 0; c < 4; ++c) {
      uint32_t k = __float_as_uint(v[c]);
      if (k) atomicAdd(&lh[k >> 20], 1u);    /* keys > 0: bin < 4096 */
    }
  }
  __syncthreads();
  for (int i = threadIdx.x; i < 4096; i += 256)
    if (lh[i]) atomicAdd(&wsu[i], lh[i]);
}

/* ---- find the bucket holding rank NUMEL (from the top) ---- */
__global__ void findbin1_k(uint32_t* __restrict__ wsu) {
  __shared__ uint32_t part[256];
  uint32_t* ctrl = wsu + 4096;
  int t = threadIdx.x;
  uint32_t s = 0;
  for (int j = 0; j < 16; ++j) s += wsu[t * 16 + j];
  part[t] = s;
  __syncthreads();
  if (t == 0) {
    uint32_t r = (uint32_t)NUMEL, cum = 0;
    int g = 255;
    for (; g > 0; --g) { if (cum + part[g] >= r) break; cum += part[g]; }
    int b = g * 16 + 15;
    for (; b > g * 16; --b) { uint32_t c = wsu[b]; if (cum + c >= r) break; cum += c; }
    ctrl[0] = (uint32_t)b;     /* b1: 12-bit bucket */
    ctrl[2] = r - cum;         /* rank to keep within bucket (1-indexed) */
  }
}

/* ---- zero below-bucket, keep above, collect in-bucket candidate indices ---- */
__global__ void mask_collect_k(f32x4v* __restrict__ f, uint32_t* __restrict__ wsu, int n4) {
  uint32_t* ctrl = wsu + 4096;
  uint32_t* cidx = wsu + CIDX_U32;
  uint32_t b1 = ctrl[0];
  int lane = threadIdx.x & 63;
  int stride = gridDim.x * 256;
  for (int i = blockIdx.x * 256 + threadIdx.x; i < n4; i += stride) {
    f32x4v v = f[i];
    f32x4v o;
    #pragma unroll
    for (int c = 0; c < 4; ++c) {
      uint32_t k = __float_as_uint(v[c]);
      uint32_t bin = k >> 20;
      o[c] = (bin >= b1) ? v[c] : 0.f;       /* candidates keep original bits */
      bool cand = (bin == b1);
      unsigned long long m = __ballot(cand ? 1 : 0);
      if (m) {                                /* wave-aggregated append */
        uint32_t base;
        int leader = __ffsll((long long)m) - 1;
        if (lane == leader) base = atomicAdd(&ctrl[6], (uint32_t)__popcll(m));
        base = __shfl(base, leader);
        if (cand) {
          uint32_t p = base + (uint32_t)__popcll(m & ((1ull << lane) - 1ull));
          if (p < CAND_CAP) cidx[p] = (uint32_t)i * 4u + (uint32_t)c;
        }
      }
    }
    f[i] = o;
  }
}

/* ---- single-block two-level tau refine + apply (ties -> keep lowest index) ---- */
__global__ __launch_bounds__(1024) void final_select_k(float* __restrict__ out,
                                                       uint32_t* __restrict__ wsu) {
  uint32_t* ctrl = wsu + 4096;
  const uint32_t* cidx = wsu + CIDX_U32;
  int t = threadIdx.x;
  uint32_t n_raw = ctrl[6];
  uint32_t n = n_raw > CAND_CAP ? CAND_CAP : n_raw;
  uint32_t r = ctrl[2];
  uint32_t b1 = ctrl[0];
  if (t == 0) {                              /* loud, decodable diagnostics */
    if (n_raw > CAND_CAP) out[0] = DIAG_CAP;
    else if (n == 0 || r == 0) out[0] = DIAG_EMPTY;
    else if (r > n) out[0] = DIAG_RANK;
  }
  if (n == 0 || r == 0 || r > n) return;

  __shared__ uint32_t lh[4096];
  __shared__ uint32_t part[1024];
  __shared__ uint32_t sup[16];
  __shared__ uint32_t sh_b2, sh_r2, sh_tau, sh_req, sh_tien;
  __shared__ uint32_t ties[4096];

  /* pass A: bits 19..8 within the bucket */
  for (int i = t; i < 4096; i += 1024) lh[i] = 0;
  __syncthreads();
  for (uint32_t j = t; j < n; j += 1024) {
    uint32_t k = __float_as_uint(out[cidx[j]]);
    atomicAdd(&lh[(k >> 8) & 4095], 1u);
  }
  __syncthreads();
  part[t] = lh[t * 4] + lh[t * 4 + 1] + lh[t * 4 + 2] + lh[t * 4 + 3];
  __syncthreads();
  if (t < 16) { uint32_t s = 0; for (int j = 0; j < 64; ++j) s += part[t * 64 + j]; sup[t] = s; }
  __syncthreads();
  if (t == 0) {
    uint32_t rem = r, cum = 0;
    int s = 15;
    for (; s > 0; --s) { if (cum + sup[s] >= rem) break; cum += sup[s]; }
    int p = s * 64 + 63;
    for (; p > s * 64; --p) { if (cum + part[p] >= rem) break; cum += part[p]; }
    int b = p * 4 + 3;
    for (; b > p * 4; --b) { if (cum + lh[b] >= rem) break; cum += lh[b]; }
    sh_b2 = (uint32_t)b;
    sh_r2 = rem - cum;
  }
  __syncthreads();
  uint32_t b2 = sh_b2, r2 = sh_r2;

  /* pass B: bits 7..0 within (b1,b2) */
  for (int i = t; i < 256; i += 1024) lh[i] = 0;
  __syncthreads();
  for (uint32_t j = t; j < n; j += 1024) {
    uint32_t k = __float_as_uint(out[cidx[j]]);
    if (((k >> 8) & 4095) == b2) atomicAdd(&lh[k & 255], 1u);
  }
  __syncthreads();
  if (t == 0) {
    uint32_t rem = r2, cum = 0;
    int b = 255;
    for (; b > 0; --b) { if (cum + lh[b] >= rem) break; cum += lh[b]; }
    sh_tau = (b1 << 20) | (b2 << 8) | (uint32_t)b;
    sh_req = rem - cum;     /* # of tau-equal elements to keep */
    sh_tien = 0;
  }
  __syncthreads();

  /* apply threshold among candidates; record tau-equal */
  uint32_t tau = sh_tau;
  for (uint32_t j = t; j < n; j += 1024) {
    uint32_t flat = cidx[j];
    uint32_t k = __float_as_uint(out[flat]);
    if (k < tau) out[flat] = 0.f;
    else if (k == tau) { uint32_t p = atomicAdd(&sh_tien, 1u); if (p < 4096) ties[p] = flat; }
  }
  __syncthreads();
  if (t == 0) {
    uint32_t m = sh_tien; if (m > 4096) m = 4096;
    uint32_t keep = sh_req;
    if (keep < m) {
      uint32_t drop = m - keep;                   /* zero the highest flat indices */
      for (uint32_t it = 0; it < drop; ++it) {
        uint32_t best = 0, bj = 0;
        for (uint32_t q = 0; q < m; ++q)
          if (ties[q] != 0xFFFFFFFFu && ties[q] >= best) { best = ties[q]; bj = q; }
        out[best] = 0.f;
        ties[bj] = 0xFFFFFFFFu;
      }
    }
  }
}

extern "C" void kernel_launch(void* const* d_in, const int* in_sizes, int n_in,
                              void* d_out, int out_size, void* d_ws, size_t ws_size,
                              hipStream_t stream) {
  const float* x  = (const float*)d_in[0];
  const float* Wv = (const float*)d_in[1];
  const float* bv = (const float*)d_in[2];
  float* out = (float*)d_out;
  uint32_t* wsu = (uint32_t*)d_ws;

  /* zero hist + ctrl every launch (replays don't re-poison) */
  hipMemsetAsync(d_ws, 0, 16384 + 64, stream);

  dim3 g(D_HID / 64, BATCH / 64);
  gemm_blas<<<g, 256, 0, stream>>>(x, Wv, bv, out);

  int n4 = BATCH * D_HID / 4;   /* 16,777,216 ; divisible by 2048*256 */
  hist1_k<<<2048, 256, 0, stream>>>((const f32x4v*)out, wsu, n4);
  findbin1_k<<<1, 256, 0, stream>>>(wsu);
  mask_collect_k<<<2048, 256, 0, stream>>>((f32x4v*)out, wsu, n4);
  final_select_k<<<1, 1024, 0, stream>>>(out, wsu);
}

// Round 9
// 2014.374 us; speedup vs baseline: 3.6401x; 3.6401x over previous
//
#include <hip/hip_runtime.h>
#include <cmath>
#include <cstdint>

#define D_IN   2048
#define D_HID  16384
#define BATCH  4096
#define NUMEL  (64 * BATCH)        /* 262144 = k * prod(batch dims) */
#define KP     (3 * D_IN)          /* 6144: bf16x3 split-K          */

#define BM 128
#define BN 128
#define BK 64

#define CAP2   32768               /* band candidates; expected ~4-8K */
#define DELTA  4.0e-3f             /* band margin >> max |f~ - f| (~1e-4) */

#define DIAG_CAP   777777.0f
#define DIAG_RANK  888888.0f
#define DIAG_EMPTY 999999.0f

/* ws layout (bytes):
   0       : u32 hist[4096]   (16 KB)
   16384   : u32 ctrl[16]     [0]=b1 [1]=r_remain [3]=prefix20 [5]=N_hi [6]=n_cand
   32768   : u32 cidx[32768]  (128 KB)
   163840  : u32 ckey[32768]  (128 KB)
   2  MiB  : bf16 A' [4096][6144]   = [x_hi | x_lo | x_hi]
   56 MiB  : bf16 B' [16384][6144]  = [w_hi | w_hi | w_lo]
   ws >= 248 MiB proven (R1/R2 ran this layout).                        */
#define CIDX_U32  8192
#define CKEY_U32  40960
#define WS_A_OFF  (2ull << 20)
#define WS_B_OFF  (56ull << 20)

typedef __bf16 v8bf  __attribute__((ext_vector_type(8)));
typedef __bf16 v4bf  __attribute__((ext_vector_type(4)));
typedef float  f32x4 __attribute__((ext_vector_type(4)));

#define GAS __attribute__((address_space(1)))
#define LAS __attribute__((address_space(3)))

__device__ __forceinline__ void gload_lds16(const void* g, void* l) {
  __builtin_amdgcn_global_load_lds((const GAS uint32_t*)g, (LAS uint32_t*)l, 16, 0, 0);
}

/* ---- fp32 -> (hi, lo) bf16 split.  mode 0: [hi|lo|hi]  mode 1: [hi|hi|lo] ---- */
__global__ void split_kernel(const float4* __restrict__ in, __bf16* __restrict__ out,
                             int n4, int mode) {
  int i = blockIdx.x * 256 + threadIdx.x;
  if (i >= n4) return;
  float4 v = in[i];
  int row = i >> 9;
  int k4  = i & 511;
  float f0 = v.x, f1 = v.y, f2 = v.z, f3 = v.w;
  __bf16 h0 = (__bf16)f0, h1 = (__bf16)f1, h2 = (__bf16)f2, h3 = (__bf16)f3;
  v4bf hi, lo;
  hi[0] = h0; hi[1] = h1; hi[2] = h2; hi[3] = h3;
  lo[0] = (__bf16)(f0 - (float)h0);
  lo[1] = (__bf16)(f1 - (float)h1);
  lo[2] = (__bf16)(f2 - (float)h2);
  lo[3] = (__bf16)(f3 - (float)h3);
  __bf16* base = out + (size_t)row * KP + (k4 << 2);
  *(v4bf*)(base)             = hi;
  *(v4bf*)(base + D_IN)      = (mode == 0) ? lo : hi;
  *(v4bf*)(base + 2 * D_IN)  = (mode == 0) ? hi : lo;
}

/* ---- m97-structure bf16x3 GEMM -> f~ (bias+relu epilogue) ---- */
__global__ __launch_bounds__(256) void gemm_bf16x3(
    const __bf16* __restrict__ A, const __bf16* __restrict__ B,
    const float* __restrict__ bias, float* __restrict__ C) {
  __shared__ __bf16 lA[BM * BK];
  __shared__ __bf16 lB[BN * BK];
  const int nwg = (BATCH / BM) * (D_HID / BN);          /* 4096, %8==0 */
  int bid = blockIdx.x;
  int swz = (bid & 7) * (nwg >> 3) + (bid >> 3);        /* XCD swizzle */
  int bn  = swz / (BATCH / BM);
  int bm  = swz % (BATCH / BM);
  int tid  = threadIdx.x;
  int lane = tid & 63;
  int w    = tid >> 6;
  int wm   = w >> 1, wn = w & 1;
  f32x4 acc[4][4] = {};
  const int lr8 = lane >> 3;
  const int lc  = (lane & 7) * 8;
  for (int kt = 0; kt < KP / BK; ++kt) {
    const int kbase = kt * BK;
    #pragma unroll
    for (int i = 0; i < 4; ++i) {
      int chunk = i * 4 + w;
      int row   = chunk * 8 + lr8;
      gload_lds16(A + (size_t)(bm * BM + row) * KP + kbase + lc, lA + chunk * 512);
      gload_lds16(B + (size_t)(bn * BN + row) * KP + kbase + lc, lB + chunk * 512);
    }
    __syncthreads();
    #pragma unroll
    for (int s = 0; s < 2; ++s) {
      v8bf af[4], bfr[4];
      #pragma unroll
      for (int mi = 0; mi < 4; ++mi)
        af[mi] = *(const v8bf*)(lA + (wm * 64 + mi * 16 + (lane & 15)) * BK + s * 32 + (lane >> 4) * 8);
      #pragma unroll
      for (int ni = 0; ni < 4; ++ni)
        bfr[ni] = *(const v8bf*)(lB + (wn * 64 + ni * 16 + (lane & 15)) * BK + s * 32 + (lane >> 4) * 8);
      #pragma unroll
      for (int mi = 0; mi < 4; ++mi)
        #pragma unroll
        for (int ni = 0; ni < 4; ++ni)
          acc[mi][ni] = __builtin_amdgcn_mfma_f32_16x16x32_bf16(af[mi], bfr[ni], acc[mi][ni], 0, 0, 0);
    }
    __syncthreads();
  }
  const int cr = (lane >> 4) * 4;
  const int cc = lane & 15;
  #pragma unroll
  for (int ni = 0; ni < 4; ++ni) {
    int col = bn * BN + wn * 64 + ni * 16 + cc;
    float bv = bias[col];
    #pragma unroll
    for (int mi = 0; mi < 4; ++mi) {
      #pragma unroll
      for (int r = 0; r < 4; ++r) {
        int rowg = bm * BM + wm * 64 + mi * 16 + cr + r;
        float v = acc[mi][ni][r] + bv;
        C[(size_t)rowg * D_HID + col] = v > 0.f ? v : 0.f;
      }
    }
  }
}

/* ---- hist pass 1: 4096 bins of top-12 key bits (skip exact zeros) ---- */
__global__ void hist1_k(const f32x4* __restrict__ f, uint32_t* __restrict__ wsu, int n4) {
  __shared__ uint32_t lh[4096];
  for (int i = threadIdx.x; i < 4096; i += 256) lh[i] = 0;
  __syncthreads();
  int stride = gridDim.x * 256;
  for (int i = blockIdx.x * 256 + threadIdx.x; i < n4; i += stride) {
    f32x4 v = f[i];
    #pragma unroll
    for (int c = 0; c < 4; ++c) {
      uint32_t k = __float_as_uint(v[c]);
      if (k) atomicAdd(&lh[k >> 20], 1u);
    }
  }
  __syncthreads();
  for (int i = threadIdx.x; i < 4096; i += 256)
    if (lh[i]) atomicAdd(&wsu[i], lh[i]);
}

__global__ void findbin1_k(uint32_t* __restrict__ wsu) {
  __shared__ uint32_t part[256];
  uint32_t* ctrl = wsu + 4096;
  int t = threadIdx.x;
  uint32_t s = 0;
  for (int j = 0; j < 16; ++j) s += wsu[t * 16 + j];
  part[t] = s;
  __syncthreads();
  if (t == 0) {
    uint32_t r = (uint32_t)NUMEL, cum = 0;
    int g = 255;
    for (; g > 0; --g) { if (cum + part[g] >= r) break; cum += part[g]; }
    int b = g * 16 + 15;
    for (; b > g * 16; --b) { uint32_t c = wsu[b]; if (cum + c >= r) break; cum += c; }
    ctrl[0] = (uint32_t)b;     /* b1 */
    ctrl[1] = r - cum;         /* rank remaining within b1 */
  }
  __syncthreads();
  for (int i = t; i < 4096; i += 256) wsu[i] = 0;   /* clear for hist2 */
}

/* ---- hist pass 2: 256 bins of key bits 19..12 within bucket b1 ---- */
__global__ void hist2_k(const f32x4* __restrict__ f, uint32_t* __restrict__ wsu, int n4) {
  __shared__ uint32_t lh[256];
  uint32_t b1 = wsu[4096];
  lh[threadIdx.x] = 0;
  __syncthreads();
  int stride = gridDim.x * 256;
  for (int i = blockIdx.x * 256 + threadIdx.x; i < n4; i += stride) {
    f32x4 v = f[i];
    #pragma unroll
    for (int c = 0; c < 4; ++c) {
      uint32_t k = __float_as_uint(v[c]);
      if ((k >> 20) == b1) atomicAdd(&lh[(k >> 12) & 255], 1u);
    }
  }
  __syncthreads();
  if (lh[threadIdx.x]) atomicAdd(&wsu[threadIdx.x], lh[threadIdx.x]);
}

__global__ void findbin2_k(uint32_t* __restrict__ wsu) {
  __shared__ uint32_t h[256];
  uint32_t* ctrl = wsu + 4096;
  int t = threadIdx.x;
  h[t] = wsu[t];
  __syncthreads();
  if (t == 0) {
    uint32_t r = ctrl[1], cum = 0;
    int b = 255;
    for (; b > 0; --b) { uint32_t c = h[b]; if (cum + c >= r) break; cum += c; }
    ctrl[3] = (ctrl[0] << 8) | (uint32_t)b;   /* 20-bit prefix containing tau~ */
  }
}

/* ---- mask + band-collect: >hi keep f~ (count), [lo,hi] -> 0 + collect, <lo -> 0 ---- */
__global__ void mask2_k(f32x4* __restrict__ f, uint32_t* __restrict__ wsu, int n4) {
  uint32_t* ctrl = wsu + 4096;
  uint32_t* cidx = wsu + CIDX_U32;
  uint32_t pfx = ctrl[3];
  float lo = __uint_as_float(pfx << 12) - DELTA;
  float hi = __uint_as_float((pfx + 1u) << 12) + DELTA;
  int lane = threadIdx.x & 63;
  uint32_t nhi = 0;
  int stride = gridDim.x * 256;
  for (int i = blockIdx.x * 256 + threadIdx.x; i < n4; i += stride) {
    f32x4 v = f[i];
    f32x4 o;
    #pragma unroll
    for (int c = 0; c < 4; ++c) {
      float val = v[c];
      bool keep = val > hi;
      bool cand = !keep && (val >= lo);
      o[c] = keep ? val : 0.f;
      if (keep) nhi++;
      unsigned long long m = __ballot(cand ? 1 : 0);
      if (m) {                                /* wave-aggregated append */
        uint32_t base;
        int leader = __ffsll((long long)m) - 1;
        if (lane == leader) base = atomicAdd(&ctrl[6], (uint32_t)__popcll(m));
        base = __shfl(base, leader);
        if (cand) {
          uint32_t p = base + (uint32_t)__popcll(m & ((1ull << lane) - 1ull));
          if (p < CAP2) cidx[p] = (uint32_t)i * 4u + (uint32_t)c;
        }
      }
    }
    f[i] = o;
  }
  #pragma unroll
  for (int off = 32; off; off >>= 1) nhi += __shfl_down(nhi, off);
  __shared__ uint32_t wred[4];
  if ((threadIdx.x & 63) == 0) wred[threadIdx.x >> 6] = nhi;
  __syncthreads();
  if (threadIdx.x == 0) atomicAdd(&ctrl[5], wred[0] + wred[1] + wred[2] + wred[3]);
}

/* ---- exact OpenBLAS-chain recompute of band candidates (1 thread/cand) ----
   BIT-IDENTICAL to R8's passing gemm_blas per element:
   kc blocks [384,384,384,384,256,256]; fmaf chain ascending k; csum += per
   block in order; + bias; relu. */
__global__ void recompute_k(const float* __restrict__ x, const float* __restrict__ W,
                            const float* __restrict__ bias, uint32_t* __restrict__ wsu) {
  uint32_t* ctrl = wsu + 4096;
  const uint32_t* cidx = wsu + CIDX_U32;
  uint32_t* ckey = wsu + CKEY_U32;
  uint32_t n = ctrl[6]; if (n > CAP2) n = CAP2;
  uint32_t j = blockIdx.x * 256 + threadIdx.x;
  if (j >= n) return;
  uint32_t flat = cidx[j];
  uint32_t row = flat >> 14;
  uint32_t col = flat & (D_HID - 1);
  const float4* xr = (const float4*)(x + (size_t)row * D_IN);
  const float4* wr = (const float4*)(W + (size_t)col * D_IN);
  const int kb_end4[6] = { 96, 192, 288, 384, 448, 512 };   /* /4 */
  float csum = 0.f;
  int k4 = 0;
  #pragma unroll
  for (int b = 0; b < 6; ++b) {
    float acc = 0.f;
    for (; k4 < kb_end4[b]; ++k4) {
      float4 a = xr[k4], w = wr[k4];
      acc = fmaf(a.x, w.x, acc);
      acc = fmaf(a.y, w.y, acc);
      acc = fmaf(a.z, w.z, acc);
      acc = fmaf(a.w, w.w, acc);
    }
    csum += acc;
  }
  float v = csum + bias[col];
  v = v > 0.f ? v : 0.f;
  ckey[j] = __float_as_uint(v);
}

/* ---- small single-block exact select on contiguous ckey[] ---- */
__global__ __launch_bounds__(1024) void select_k(float* __restrict__ out,
                                                 uint32_t* __restrict__ wsu) {
  uint32_t* ctrl = wsu + 4096;
  const uint32_t* cidx = wsu + CIDX_U32;
  const uint32_t* ckey = wsu + CKEY_U32;
  int t = threadIdx.x;
  uint32_t n_raw = ctrl[6];
  uint32_t n = n_raw > CAP2 ? CAP2 : n_raw;
  uint32_t nhi = ctrl[5];
  int r_keep = (int)(uint32_t)NUMEL - (int)nhi;
  if (t == 0) {
    if (n_raw > CAP2) out[0] = DIAG_CAP;
    else if (n == 0) out[0] = DIAG_EMPTY;
    else if (r_keep < 0 || (uint32_t)r_keep > n) out[0] = DIAG_RANK;
  }
  if (n == 0 || r_keep <= 0 || (uint32_t)r_keep > n) return;

  __shared__ uint32_t lh[256];
  __shared__ uint32_t sh_b, sh_rem, sh_tien;
  __shared__ uint32_t ties[1024];

  uint32_t prefix = 0;
  uint32_t rem = (uint32_t)r_keep;
  for (int s = 24; s >= 0; s -= 8) {
    for (int i = t; i < 256; i += 1024) lh[i] = 0;
    __syncthreads();
    for (uint32_t j = t; j < n; j += 1024) {
      uint32_t key = ckey[j];
      if (s == 24 || (key >> (s + 8)) == prefix)
        atomicAdd(&lh[(key >> s) & 255], 1u);
    }
    __syncthreads();
    if (t == 0) {
      uint32_t cum = 0;
      int b = 255;
      for (; b > 0; --b) { uint32_t c = lh[b]; if (cum + c >= rem) break; cum += c; }
      sh_b = (uint32_t)b;
      sh_rem = rem - cum;
    }
    __syncthreads();
    prefix = (prefix << 8) | sh_b;
    rem = sh_rem;
    __syncthreads();
  }
  uint32_t tau = prefix;       /* exact threshold key */
  uint32_t req = rem;          /* # of tau-equal to keep */
  if (t == 0) sh_tien = 0;
  __syncthreads();
  for (uint32_t j = t; j < n; j += 1024) {
    uint32_t key = ckey[j];
    if (key > tau) out[cidx[j]] = __uint_as_float(key);
    else if (key == tau) { uint32_t p = atomicAdd(&sh_tien, 1u); if (p < 1024) ties[p] = cidx[j]; }
  }
  __syncthreads();
  if (t == 0) {
    uint32_t m = sh_tien; if (m > 1024) m = 1024;
    if (req < m) {                               /* drop the (m-req) highest indices */
      uint32_t drop = m - req;
      for (uint32_t it = 0; it < drop; ++it) {
        uint32_t best = 0, bj = 0;
        for (uint32_t q = 0; q < m; ++q)
          if (ties[q] != 0xFFFFFFFFu && ties[q] >= best) { best = ties[q]; bj = q; }
        ties[bj] = 0xFFFFFFFFu;
      }
    }
    float tv = __uint_as_float(tau);
    for (uint32_t q = 0; q < m; ++q)
      if (ties[q] != 0xFFFFFFFFu) out[ties[q]] = tv;
  }
}

extern "C" void kernel_launch(void* const* d_in, const int* in_sizes, int n_in,
                              void* d_out, int out_size, void* d_ws, size_t ws_size,
                              hipStream_t stream) {
  const float* x  = (const float*)d_in[0];
  const float* Wv = (const float*)d_in[1];
  const float* bv = (const float*)d_in[2];
  float* out = (float*)d_out;
  uint8_t* ws = (uint8_t*)d_ws;
  uint32_t* wsu = (uint32_t*)d_ws;

  /* zero hist + ctrl every launch (replays don't re-poison) */
  hipMemsetAsync(d_ws, 0, 16384 + 64, stream);

  __bf16* Ap = (__bf16*)(ws + WS_A_OFF);
  __bf16* Bp = (__bf16*)(ws + WS_B_OFF);
  int nx4 = BATCH * D_IN / 4;
  int nw4 = D_HID * D_IN / 4;
  split_kernel<<<nx4 / 256, 256, 0, stream>>>((const float4*)x,  Ap, nx4, 0);
  split_kernel<<<nw4 / 256, 256, 0, stream>>>((const float4*)Wv, Bp, nw4, 1);
  gemm_bf16x3<<<(BATCH / BM) * (D_HID / BN), 256, 0, stream>>>(Ap, Bp, bv, out);

  int n4 = BATCH * D_HID / 4;   /* 16,777,216 */
  hist1_k<<<2048, 256, 0, stream>>>((const f32x4*)out, wsu, n4);
  findbin1_k<<<1, 256, 0, stream>>>(wsu);
  hist2_k<<<2048, 256, 0, stream>>>((const f32x4*)out, wsu, n4);
  findbin2_k<<<1, 256, 0, stream>>>(wsu);
  mask2_k<<<2048, 256, 0, stream>>>((f32x4*)out, wsu, n4);
  recompute_k<<<CAP2 / 256, 256, 0, stream>>>(x, Wv, bv, wsu);
  select_k<<<1, 1024, 0, stream>>>(out, wsu);
}

// Round 10
// 1852.789 us; speedup vs baseline: 3.9576x; 1.0872x over previous
//
#include <hip/hip_runtime.h>
#include <cmath>
#include <cstdint>

#define D_IN   2048
#define D_HID  16384
#define BATCH  4096
#define NUMEL  (64 * BATCH)        /* 262144 = k * prod(batch dims) */
#define KP     (3 * D_IN)          /* 6144: bf16x3 split-K          */

#define BM 128
#define BN 128
#define BK 64

#define CAP2   32768               /* band candidates; expected ~4-8K */
#define DELTA  4.0e-3f             /* band margin >> max |f~ - f| (~1e-4) */

#define DIAG_CAP   777777.0f
#define DIAG_RANK  888888.0f
#define DIAG_EMPTY 999999.0f

/* ws layout (bytes):
   0       : u32 hist[4096]   (16 KB)
   16384   : u32 ctrl[16]     [0]=b1 [1]=r_remain [3]=prefix20 [5]=N_hi [6]=n_cand
   32768   : u32 cidx[32768]  (128 KB)
   163840  : u32 ckey[32768]  (128 KB)
   2  MiB  : bf16 A' [4096][6144]   = [x_hi | x_lo | x_hi]
   56 MiB  : bf16 B' [16384][6144]  = [w_hi | w_hi | w_lo]                */
#define CIDX_U32  8192
#define CKEY_U32  40960
#define WS_A_OFF  (2ull << 20)
#define WS_B_OFF  (56ull << 20)

typedef __bf16 v8bf  __attribute__((ext_vector_type(8)));
typedef __bf16 v4bf  __attribute__((ext_vector_type(4)));
typedef float  f32x4 __attribute__((ext_vector_type(4)));

#define GAS __attribute__((address_space(1)))
#define LAS __attribute__((address_space(3)))

__device__ __forceinline__ void gload_lds16(const void* g, void* l) {
  __builtin_amdgcn_global_load_lds((const GAS uint32_t*)g, (LAS uint32_t*)l, 16, 0, 0);
}

/* ---- fused fp32 -> bf16x3 split for x and W in one launch ----
   x blocks: [0, 8192)  mode0: [hi|lo|hi] ; W blocks: [8192, 40960) mode1: [hi|hi|lo] */
__global__ void split_both(const float4* __restrict__ x, const float4* __restrict__ w,
                           __bf16* __restrict__ Ap, __bf16* __restrict__ Bp) {
  int bid = blockIdx.x;
  const float4* in;
  __bf16* out;
  int i, mode;
  if (bid < 8192) { in = x; out = Ap; i = bid * 256 + threadIdx.x; mode = 0; }
  else            { in = w; out = Bp; i = (bid - 8192) * 256 + threadIdx.x; mode = 1; }
  float4 v = in[i];
  int row = i >> 9;           /* / (D_IN/4) */
  int k4  = i & 511;
  float f0 = v.x, f1 = v.y, f2 = v.z, f3 = v.w;
  __bf16 h0 = (__bf16)f0, h1 = (__bf16)f1, h2 = (__bf16)f2, h3 = (__bf16)f3;
  v4bf hi, lo;
  hi[0] = h0; hi[1] = h1; hi[2] = h2; hi[3] = h3;
  lo[0] = (__bf16)(f0 - (float)h0);
  lo[1] = (__bf16)(f1 - (float)h1);
  lo[2] = (__bf16)(f2 - (float)h2);
  lo[3] = (__bf16)(f3 - (float)h3);
  __bf16* base = out + (size_t)row * KP + (k4 << 2);
  *(v4bf*)(base)             = hi;
  *(v4bf*)(base + D_IN)      = (mode == 0) ? lo : hi;
  *(v4bf*)(base + 2 * D_IN)  = (mode == 0) ? hi : lo;
}

/* ---- m97-structure bf16x3 GEMM, XOR-swizzled LDS, fused hist1 epilogue ----
   Swizzle (rule #21, both-sides): LDS dest linear (global_load_lds);
   global SOURCE fetches 16B-chunk ((lane&7)^(lane>>3)) of its row;
   ds_read uses physical slot = logical_slot ^ (row&7).                  */
__global__ __launch_bounds__(256) void gemm_bf16x3(
    const __bf16* __restrict__ A, const __bf16* __restrict__ B,
    const float* __restrict__ bias, float* __restrict__ C,
    uint32_t* __restrict__ ghist) {
  __shared__ __bf16 lA[BM * BK];
  __shared__ __bf16 lB[BN * BK];
  const int nwg = (BATCH / BM) * (D_HID / BN);          /* 4096, %8==0 */
  int bid = blockIdx.x;
  int swz = (bid & 7) * (nwg >> 3) + (bid >> 3);        /* XCD swizzle */
  int bn  = swz / (BATCH / BM);
  int bm  = swz % (BATCH / BM);
  int tid  = threadIdx.x;
  int lane = tid & 63;
  int w    = tid >> 6;
  int wm   = w >> 1, wn = w & 1;
  f32x4 acc[4][4] = {};
  const int lr8    = lane >> 3;                     /* row within 8-row chunk  */
  const int lc_swz = (((lane & 7) ^ lr8) * 8);      /* inverse-swizzled source */
  for (int kt = 0; kt < KP / BK; ++kt) {
    const int kbase = kt * BK;
    #pragma unroll
    for (int i = 0; i < 4; ++i) {
      int chunk = i * 4 + w;
      int row   = chunk * 8 + lr8;
      gload_lds16(A + (size_t)(bm * BM + row) * KP + kbase + lc_swz, lA + chunk * 512);
      gload_lds16(B + (size_t)(bn * BN + row) * KP + kbase + lc_swz, lB + chunk * 512);
    }
    __syncthreads();
    #pragma unroll
    for (int s = 0; s < 2; ++s) {
      const int ls = s * 4 + (lane >> 4);           /* logical 16B slot 0..7 */
      v8bf af[4], bfr[4];
      #pragma unroll
      for (int mi = 0; mi < 4; ++mi) {
        int row = wm * 64 + mi * 16 + (lane & 15);
        af[mi] = *(const v8bf*)(lA + row * BK + ((ls ^ (row & 7)) * 8));
      }
      #pragma unroll
      for (int ni = 0; ni < 4; ++ni) {
        int row = wn * 64 + ni * 16 + (lane & 15);
        bfr[ni] = *(const v8bf*)(lB + row * BK + ((ls ^ (row & 7)) * 8));
      }
      #pragma unroll
      for (int mi = 0; mi < 4; ++mi)
        #pragma unroll
        for (int ni = 0; ni < 4; ++ni)
          acc[mi][ni] = __builtin_amdgcn_mfma_f32_16x16x32_bf16(af[mi], bfr[ni], acc[mi][ni], 0, 0, 0);
    }
    __syncthreads();
  }

  /* epilogue: C write + fused 4096-bin histogram (reuse lA as LDS hist) */
  uint32_t* h = (uint32_t*)lA;                      /* 16 KB = 4096 u32 */
  #pragma unroll
  for (int i = tid; i < 4096; i += 256) h[i] = 0;
  __syncthreads();
  const int cr = (lane >> 4) * 4;
  const int cc = lane & 15;
  #pragma unroll
  for (int ni = 0; ni < 4; ++ni) {
    int col = bn * BN + wn * 64 + ni * 16 + cc;
    float bv = bias[col];
    #pragma unroll
    for (int mi = 0; mi < 4; ++mi) {
      #pragma unroll
      for (int r = 0; r < 4; ++r) {
        int rowg = bm * BM + wm * 64 + mi * 16 + cr + r;
        float v = acc[mi][ni][r] + bv;
        v = v > 0.f ? v : 0.f;
        C[(size_t)rowg * D_HID + col] = v;
        uint32_t k = __float_as_uint(v);
        if (k) atomicAdd(&h[k >> 20], 1u);
      }
    }
  }
  __syncthreads();
  for (int i = tid; i < 4096; i += 256)
    if (h[i]) atomicAdd(&ghist[i], h[i]);
}

__global__ void findbin1_k(uint32_t* __restrict__ wsu) {
  __shared__ uint32_t part[256];
  uint32_t* ctrl = wsu + 4096;
  int t = threadIdx.x;
  uint32_t s = 0;
  for (int j = 0; j < 16; ++j) s += wsu[t * 16 + j];
  part[t] = s;
  __syncthreads();
  if (t == 0) {
    uint32_t r = (uint32_t)NUMEL, cum = 0;
    int g = 255;
    for (; g > 0; --g) { if (cum + part[g] >= r) break; cum += part[g]; }
    int b = g * 16 + 15;
    for (; b > g * 16; --b) { uint32_t c = wsu[b]; if (cum + c >= r) break; cum += c; }
    ctrl[0] = (uint32_t)b;     /* b1 */
    ctrl[1] = r - cum;         /* rank remaining within b1 */
  }
  __syncthreads();
  for (int i = t; i < 4096; i += 256) wsu[i] = 0;   /* clear for hist2 */
}

/* ---- hist pass 2: 256 bins of key bits 19..12 within bucket b1 ---- */
__global__ void hist2_k(const f32x4* __restrict__ f, uint32_t* __restrict__ wsu, int n4) {
  __shared__ uint32_t lh[256];
  uint32_t b1 = wsu[4096];
  lh[threadIdx.x] = 0;
  __syncthreads();
  int stride = gridDim.x * 256;
  for (int i = blockIdx.x * 256 + threadIdx.x; i < n4; i += stride) {
    f32x4 v = f[i];
    #pragma unroll
    for (int c = 0; c < 4; ++c) {
      uint32_t k = __float_as_uint(v[c]);
      if ((k >> 20) == b1) atomicAdd(&lh[(k >> 12) & 255], 1u);
    }
  }
  __syncthreads();
  if (lh[threadIdx.x]) atomicAdd(&wsu[threadIdx.x], lh[threadIdx.x]);
}

__global__ void findbin2_k(uint32_t* __restrict__ wsu) {
  __shared__ uint32_t h[256];
  uint32_t* ctrl = wsu + 4096;
  int t = threadIdx.x;
  h[t] = wsu[t];
  __syncthreads();
  if (t == 0) {
    uint32_t r = ctrl[1], cum = 0;
    int b = 255;
    for (; b > 0; --b) { uint32_t c = h[b]; if (cum + c >= r) break; cum += c; }
    ctrl[3] = (ctrl[0] << 8) | (uint32_t)b;   /* 20-bit prefix containing tau~ */
  }
}

/* ---- mask + band-collect: >hi keep f~ (count), [lo,hi] -> 0 + collect, <lo -> 0 ---- */
__global__ void mask2_k(f32x4* __restrict__ f, uint32_t* __restrict__ wsu, int n4) {
  uint32_t* ctrl = wsu + 4096;
  uint32_t* cidx = wsu + CIDX_U32;
  uint32_t pfx = ctrl[3];
  float lo = __uint_as_float(pfx << 12) - DELTA;
  float hi = __uint_as_float((pfx + 1u) << 12) + DELTA;
  int lane = threadIdx.x & 63;
  uint32_t nhi = 0;
  int stride = gridDim.x * 256;
  for (int i = blockIdx.x * 256 + threadIdx.x; i < n4; i += stride) {
    f32x4 v = f[i];
    f32x4 o;
    #pragma unroll
    for (int c = 0; c < 4; ++c) {
      float val = v[c];
      bool keep = val > hi;
      bool cand = !keep && (val >= lo);
      o[c] = keep ? val : 0.f;
      if (keep) nhi++;
      unsigned long long m = __ballot(cand ? 1 : 0);
      if (m) {                                /* wave-aggregated append */
        uint32_t base;
        int leader = __ffsll((long long)m) - 1;
        if (lane == leader) base = atomicAdd(&ctrl[6], (uint32_t)__popcll(m));
        base = __shfl(base, leader);
        if (cand) {
          uint32_t p = base + (uint32_t)__popcll(m & ((1ull << lane) - 1ull));
          if (p < CAP2) cidx[p] = (uint32_t)i * 4u + (uint32_t)c;
        }
      }
    }
    f[i] = o;
  }
  #pragma unroll
  for (int off = 32; off; off >>= 1) nhi += __shfl_down(nhi, off);
  __shared__ uint32_t wred[4];
  if ((threadIdx.x & 63) == 0) wred[threadIdx.x >> 6] = nhi;
  __syncthreads();
  if (threadIdx.x == 0) atomicAdd(&ctrl[5], wred[0] + wred[1] + wred[2] + wred[3]);
}

/* ---- exact OpenBLAS-chain recompute of band candidates (1 thread/cand) ---- */
__global__ void recompute_k(const float* __restrict__ x, const float* __restrict__ W,
                            const float* __restrict__ bias, uint32_t* __restrict__ wsu) {
  uint32_t* ctrl = wsu + 4096;
  const uint32_t* cidx = wsu + CIDX_U32;
  uint32_t* ckey = wsu + CKEY_U32;
  uint32_t n = ctrl[6]; if (n > CAP2) n = CAP2;
  uint32_t j = blockIdx.x * 256 + threadIdx.x;
  if (j >= n) return;
  uint32_t flat = cidx[j];
  uint32_t row = flat >> 14;
  uint32_t col = flat & (D_HID - 1);
  const float4* xr = (const float4*)(x + (size_t)row * D_IN);
  const float4* wr = (const float4*)(W + (size_t)col * D_IN);
  const int kb_end4[6] = { 96, 192, 288, 384, 448, 512 };   /* /4 */
  float csum = 0.f;
  int k4 = 0;
  #pragma unroll
  for (int b = 0; b < 6; ++b) {
    float acc = 0.f;
    for (; k4 < kb_end4[b]; ++k4) {
      float4 a = xr[k4], w = wr[k4];
      acc = fmaf(a.x, w.x, acc);
      acc = fmaf(a.y, w.y, acc);
      acc = fmaf(a.z, w.z, acc);
      acc = fmaf(a.w, w.w, acc);
    }
    csum += acc;
  }
  float v = csum + bias[col];
  v = v > 0.f ? v : 0.f;
  ckey[j] = __float_as_uint(v);
}

/* ---- small single-block exact select on contiguous ckey[] ---- */
__global__ __launch_bounds__(1024) void select_k(float* __restrict__ out,
                                                 uint32_t* __restrict__ wsu) {
  uint32_t* ctrl = wsu + 4096;
  const uint32_t* cidx = wsu + CIDX_U32;
  const uint32_t* ckey = wsu + CKEY_U32;
  int t = threadIdx.x;
  uint32_t n_raw = ctrl[6];
  uint32_t n = n_raw > CAP2 ? CAP2 : n_raw;
  uint32_t nhi = ctrl[5];
  int r_keep = (int)(uint32_t)NUMEL - (int)nhi;
  if (t == 0) {
    if (n_raw > CAP2) out[0] = DIAG_CAP;
    else if (n == 0) out[0] = DIAG_EMPTY;
    else if (r_keep < 0 || (uint32_t)r_keep > n) out[0] = DIAG_RANK;
  }
  if (n == 0 || r_keep <= 0 || (uint32_t)r_keep > n) return;

  __shared__ uint32_t lh[256];
  __shared__ uint32_t sh_b, sh_rem, sh_tien;
  __shared__ uint32_t ties[1024];

  uint32_t prefix = 0;
  uint32_t rem = (uint32_t)r_keep;
  for (int s = 24; s >= 0; s -= 8) {
    for (int i = t; i < 256; i += 1024) lh[i] = 0;
    __syncthreads();
    for (uint32_t j = t; j < n; j += 1024) {
      uint32_t key = ckey[j];
      if (s == 24 || (key >> (s + 8)) == prefix)
        atomicAdd(&lh[(key >> s) & 255], 1u);
    }
    __syncthreads();
    if (t == 0) {
      uint32_t cum = 0;
      int b = 255;
      for (; b > 0; --b) { uint32_t c = lh[b]; if (cum + c >= rem) break; cum += c; }
      sh_b = (uint32_t)b;
      sh_rem = rem - cum;
    }
    __syncthreads();
    prefix = (prefix << 8) | sh_b;
    rem = sh_rem;
    __syncthreads();
  }
  uint32_t tau = prefix;       /* exact threshold key */
  uint32_t req = rem;          /* # of tau-equal to keep */
  if (t == 0) sh_tien = 0;
  __syncthreads();
  for (uint32_t j = t; j < n; j += 1024) {
    uint32_t key = ckey[j];
    if (key > tau) out[cidx[j]] = __uint_as_float(key);
    else if (key == tau) { uint32_t p = atomicAdd(&sh_tien, 1u); if (p < 1024) ties[p] = cidx[j]; }
  }
  __syncthreads();
  if (t == 0) {
    uint32_t m = sh_tien; if (m > 1024) m = 1024;
    if (req < m) {                               /* drop the (m-req) highest indices */
      uint32_t drop = m - req;
      for (uint32_t it = 0; it < drop; ++it) {
        uint32_t best = 0, bj = 0;
        for (uint32_t q = 0; q < m; ++q)
          if (ties[q] != 0xFFFFFFFFu && ties[q] >= best) { best = ties[q]; bj = q; }
        ties[bj] = 0xFFFFFFFFu;
      }
    }
    float tv = __uint_as_float(tau);
    for (uint32_t q = 0; q < m; ++q)
      if (ties[q] != 0xFFFFFFFFu) out[ties[q]] = tv;
  }
}

extern "C" void kernel_launch(void* const* d_in, const int* in_sizes, int n_in,
                              void* d_out, int out_size, void* d_ws, size_t ws_size,
                              hipStream_t stream) {
  const float* x  = (const float*)d_in[0];
  const float* Wv = (const float*)d_in[1];
  const float* bv = (const float*)d_in[2];
  float* out = (float*)d_out;
  uint8_t* ws = (uint8_t*)d_ws;
  uint32_t* wsu = (uint32_t*)d_ws;

  /* zero hist + ctrl every launch (replays don't re-poison) */
  hipMemsetAsync(d_ws, 0, 16384 + 64, stream);

  __bf16* Ap = (__bf16*)(ws + WS_A_OFF);
  __bf16* Bp = (__bf16*)(ws + WS_B_OFF);
  split_both<<<40960, 256, 0, stream>>>((const float4*)x, (const float4*)Wv, Ap, Bp);
  gemm_bf16x3<<<(BATCH / BM) * (D_HID / BN), 256, 0, stream>>>(Ap, Bp, bv, out, wsu);

  int n4 = BATCH * D_HID / 4;   /* 16,777,216 */
  findbin1_k<<<1, 256, 0, stream>>>(wsu);
  hist2_k<<<2048, 256, 0, stream>>>((const f32x4*)out, wsu, n4);
  findbin2_k<<<1, 256, 0, stream>>>(wsu);
  mask2_k<<<2048, 256, 0, stream>>>((f32x4*)out, wsu, n4);
  recompute_k<<<CAP2 / 256, 256, 0, stream>>>(x, Wv, bv, wsu);
  select_k<<<1, 1024, 0, stream>>>(out, wsu);
}